// Round 2
// baseline (61.265 us; speedup 1.0000x reference)
//
#include <hip/hip_runtime.h>
#include <hip/hip_bf16.h>

// Causal depthwise conv1d (K=4) + SiLU over x:(B,S,D) fp32, w:(D,1,4) fp32.
// y[b,s,d] = silu(sum_k w[d,k] * x[b, s-3+k, d])
//
// R1 changes vs R0:
//  - Hoist ALL (TS+3) float4 loads into registers up front (explicit array,
//    fully unrolled -> static indices -> VGPRs). R0's VGPR=44 proved the
//    compiler issued loads in small groups; this maximizes loads-in-flight
//    per wave (MLP) against ~900cy HBM latency.
//  - SiLU via v_rcp_f32 (__builtin_amdgcn_rcpf) instead of IEEE divide
//    (div_scale/div_fmas/div_fixup ~10 VALU ops/elem).

#define TS 8  // s-positions per thread; halo read amplification (TS+3)/TS = 1.375

__device__ __forceinline__ float fast_silu(float v) {
    // v * sigmoid(v) = v / (1 + exp(-v)); rcp approx is ~1ulp, threshold 3.9e-2
    float e = __expf(-v);
    return v * __builtin_amdgcn_rcpf(1.0f + e);
}

__global__ __launch_bounds__(256) void causal_conv1d_silu_kernel(
    const float4* __restrict__ x,   // (B,S,D/4) float4
    const float4* __restrict__ w4,  // (D,) float4: w4[d] = taps k=0..3 of channel d
    float4* __restrict__ y,
    int B, int S, int D4)           // D4 = D/4
{
    const int t = blockIdx.x * blockDim.x + threadIdx.x;
    const int n_stiles = S / TS;
    const int d4 = t % D4;
    const int rest = t / D4;
    if (rest >= B * n_stiles) return;
    const int stile = rest % n_stiles;
    const int b = rest / n_stiles;
    const int s0 = stile * TS;

    const size_t base = (size_t)b * S * D4 + d4;
    const float4* xp = x + base;
    float4* yp = y + base;

    // ---- load burst: weights + all TS+3 x rows, all in flight at once ----
    const float4 wa = w4[d4 * 4 + 0];
    const float4 wb = w4[d4 * 4 + 1];
    const float4 wc = w4[d4 * 4 + 2];
    const float4 wd = w4[d4 * 4 + 3];

    const float4 zero = make_float4(0.f, 0.f, 0.f, 0.f);
    float4 xs[TS + 3];
    // halo (wave-uniform predicates: s0 identical across the wave's lanes)
    xs[0] = (s0 >= 3) ? xp[(size_t)(s0 - 3) * D4] : zero;
    xs[1] = (s0 >= 2) ? xp[(size_t)(s0 - 2) * D4] : zero;
    xs[2] = (s0 >= 1) ? xp[(size_t)(s0 - 1) * D4] : zero;
#pragma unroll
    for (int i = 0; i < TS; ++i) {
        xs[i + 3] = xp[(size_t)(s0 + i) * D4];
    }

    // ---- compute + store ----
#pragma unroll
    for (int i = 0; i < TS; ++i) {
        const float4 xm3 = xs[i];
        const float4 xm2 = xs[i + 1];
        const float4 xm1 = xs[i + 2];
        const float4 xc  = xs[i + 3];
        float4 o;
        o.x = fast_silu(wa.x * xm3.x + wa.y * xm2.x + wa.z * xm1.x + wa.w * xc.x);
        o.y = fast_silu(wb.x * xm3.y + wb.y * xm2.y + wb.z * xm1.y + wb.w * xc.y);
        o.z = fast_silu(wc.x * xm3.z + wc.y * xm2.z + wc.z * xm1.z + wc.w * xc.z);
        o.w = fast_silu(wd.x * xm3.w + wd.y * xm2.w + wd.z * xm1.w + wd.w * xc.w);
        yp[(size_t)(s0 + i) * D4] = o;
    }
}

extern "C" void kernel_launch(void* const* d_in, const int* in_sizes, int n_in,
                              void* d_out, int out_size, void* d_ws, size_t ws_size,
                              hipStream_t stream) {
    const float* x = (const float*)d_in[0];
    const float* w = (const float*)d_in[1];
    float* y = (float*)d_out;

    // x: (B, S, D) = (4, 4096, 2048); w: (D, 1, 4)
    const int D = in_sizes[1] / 4;     // 2048
    const int D4 = D / 4;              // 512
    const int BS = in_sizes[0] / D;    // B*S = 16384
    const int S = 4096;
    const int B = BS / S;              // 4

    const int n_stiles = S / TS;
    const long long total_threads = (long long)B * n_stiles * D4;
    const int block = 256;
    const int grid = (int)((total_threads + block - 1) / block);

    causal_conv1d_silu_kernel<<<grid, block, 0, stream>>>(
        (const float4*)x, (const float4*)w, (float4*)y, B, S, D4);
}

// Round 4
// 52.504 us; speedup vs baseline: 1.1669x; 1.1669x over previous
//
#include <hip/hip_runtime.h>
#include <hip/hip_bf16.h>

// Causal depthwise conv1d (K=4) + SiLU over x:(B,S,D) fp32, w:(D,1,4) fp32.
// y[b,s,d] = silu(sum_k w[d,k] * x[b, s-3+k, d])
//
// R3 = R2 with the nontemporal store fixed: __builtin_nontemporal_store needs
// a clang ext_vector type, not HIP's float4 class. Same theory as R2:
//  - __launch_bounds__(256, 2): VGPR budget up to 256 so the TS+3 float4 load
//    burst stays in flight (R1 VGPR=48 proved the compiler sank the loads).
//  - NT stores for y (never re-read): keep L2/L3 for the x halo rows.

#define TS 8  // s-positions per thread; halo amplification (TS+3)/TS = 1.375

typedef float floatx4 __attribute__((ext_vector_type(4)));

__device__ __forceinline__ float fast_silu(float v) {
    float e = __expf(-v);
    return v * __builtin_amdgcn_rcpf(1.0f + e);
}

__global__ __launch_bounds__(256, 2) void causal_conv1d_silu_kernel(
    const float4* __restrict__ x,   // (B,S,D/4) float4
    const float4* __restrict__ w4,  // (D,) float4: w4[d] = taps k=0..3 of channel d
    float4* __restrict__ y,
    int B, int S, int D4)           // D4 = D/4
{
    const int t = blockIdx.x * blockDim.x + threadIdx.x;
    const int n_stiles = S / TS;
    const int d4 = t % D4;
    const int rest = t / D4;
    if (rest >= B * n_stiles) return;
    const int stile = rest % n_stiles;
    const int b = rest / n_stiles;
    const int s0 = stile * TS;

    const size_t base = (size_t)b * S * D4 + d4;
    const float4* xp = x + base;
    floatx4* yp = (floatx4*)(y + base);

    // ---- load burst: all TS+3 x rows + 4 weight rows, in flight together ----
    const float4 zero = make_float4(0.f, 0.f, 0.f, 0.f);
    float4 xs[TS + 3];
    xs[0] = (s0 >= 3) ? xp[(size_t)(s0 - 3) * D4] : zero;
    xs[1] = (s0 >= 2) ? xp[(size_t)(s0 - 2) * D4] : zero;
    xs[2] = (s0 >= 1) ? xp[(size_t)(s0 - 1) * D4] : zero;
#pragma unroll
    for (int i = 0; i < TS; ++i) {
        xs[i + 3] = xp[(size_t)(s0 + i) * D4];
    }
    const float4 wa = w4[d4 * 4 + 0];
    const float4 wb = w4[d4 * 4 + 1];
    const float4 wc = w4[d4 * 4 + 2];
    const float4 wd = w4[d4 * 4 + 3];

    // ---- compute + nontemporal store ----
#pragma unroll
    for (int i = 0; i < TS; ++i) {
        const float4 xm3 = xs[i];
        const float4 xm2 = xs[i + 1];
        const float4 xm1 = xs[i + 2];
        const float4 xc  = xs[i + 3];
        floatx4 o;
        o.x = fast_silu(wa.x * xm3.x + wa.y * xm2.x + wa.z * xm1.x + wa.w * xc.x);
        o.y = fast_silu(wb.x * xm3.y + wb.y * xm2.y + wb.z * xm1.y + wb.w * xc.y);
        o.z = fast_silu(wc.x * xm3.z + wc.y * xm2.z + wc.z * xm1.z + wc.w * xc.z);
        o.w = fast_silu(wd.x * xm3.w + wd.y * xm2.w + wd.z * xm1.w + wd.w * xc.w);
        __builtin_nontemporal_store(o, &yp[(size_t)(s0 + i) * D4]);
    }
}

extern "C" void kernel_launch(void* const* d_in, const int* in_sizes, int n_in,
                              void* d_out, int out_size, void* d_ws, size_t ws_size,
                              hipStream_t stream) {
    const float* x = (const float*)d_in[0];
    const float* w = (const float*)d_in[1];
    float* y = (float*)d_out;

    // x: (B, S, D) = (4, 4096, 2048); w: (D, 1, 4)
    const int D = in_sizes[1] / 4;     // 2048
    const int D4 = D / 4;              // 512
    const int BS = in_sizes[0] / D;    // B*S = 16384
    const int S = 4096;
    const int B = BS / S;              // 4

    const int n_stiles = S / TS;
    const long long total_threads = (long long)B * n_stiles * D4;
    const int block = 256;
    const int grid = (int)((total_threads + block - 1) / block);

    causal_conv1d_silu_kernel<<<grid, block, 0, stream>>>(
        (const float4*)x, (const float4*)w, (float4*)y, B, S, D4);
}

// Round 5
// 48.982 us; speedup vs baseline: 1.2508x; 1.0719x over previous
//
#include <hip/hip_runtime.h>
#include <hip/hip_bf16.h>

// Causal depthwise conv1d (K=4) + SiLU over x:(B,S,D) fp32, w:(D,1,4) fp32.
// y[b,s,d] = silu(sum_k w[d,k] * x[b, s-3+k, d])
//
// R4 changes vs R3 (52.5us):
//  - TS 8 -> 16: halo read ratio 1.375 -> 1.19, VMEM instrs/output 2.4 -> 2.2,
//    per-tile prologue amortized over 2x outputs. Fits VGPR budget from
//    __launch_bounds__(256,2): 19 float4 xs (76) + 4 float4 w (16) + addr ~ 110.
//  - Keep NT stores (y never re-read) and the up-front load burst.

#define TS 16  // s-positions per thread; halo amplification (TS+3)/TS = 1.1875

typedef float floatx4 __attribute__((ext_vector_type(4)));

__device__ __forceinline__ float fast_silu(float v) {
    float e = __expf(-v);
    return v * __builtin_amdgcn_rcpf(1.0f + e);
}

__global__ __launch_bounds__(256, 2) void causal_conv1d_silu_kernel(
    const float4* __restrict__ x,   // (B,S,D/4) float4
    const float4* __restrict__ w4,  // (D,) float4: w4[d] = taps k=0..3 of channel d
    float4* __restrict__ y,
    int B, int S, int D4)           // D4 = D/4
{
    const int t = blockIdx.x * blockDim.x + threadIdx.x;
    const int n_stiles = S / TS;
    const int d4 = t % D4;
    const int rest = t / D4;
    if (rest >= B * n_stiles) return;
    const int stile = rest % n_stiles;
    const int b = rest / n_stiles;
    const int s0 = stile * TS;

    const size_t base = (size_t)b * S * D4 + d4;
    const float4* xp = x + base;
    floatx4* yp = (floatx4*)(y + base);

    // ---- load burst: all TS+3 x rows + 4 weight rows, in flight together ----
    const float4 zero = make_float4(0.f, 0.f, 0.f, 0.f);
    float4 xs[TS + 3];
    xs[0] = (s0 >= 3) ? xp[(size_t)(s0 - 3) * D4] : zero;
    xs[1] = (s0 >= 2) ? xp[(size_t)(s0 - 2) * D4] : zero;
    xs[2] = (s0 >= 1) ? xp[(size_t)(s0 - 1) * D4] : zero;
#pragma unroll
    for (int i = 0; i < TS; ++i) {
        xs[i + 3] = xp[(size_t)(s0 + i) * D4];
    }
    const float4 wa = w4[d4 * 4 + 0];
    const float4 wb = w4[d4 * 4 + 1];
    const float4 wc = w4[d4 * 4 + 2];
    const float4 wd = w4[d4 * 4 + 3];

    // ---- compute + nontemporal store ----
#pragma unroll
    for (int i = 0; i < TS; ++i) {
        const float4 xm3 = xs[i];
        const float4 xm2 = xs[i + 1];
        const float4 xm1 = xs[i + 2];
        const float4 xc  = xs[i + 3];
        floatx4 o;
        o.x = fast_silu(wa.x * xm3.x + wa.y * xm2.x + wa.z * xm1.x + wa.w * xc.x);
        o.y = fast_silu(wb.x * xm3.y + wb.y * xm2.y + wb.z * xm1.y + wb.w * xc.y);
        o.z = fast_silu(wc.x * xm3.z + wc.y * xm2.z + wc.z * xm1.z + wc.w * xc.z);
        o.w = fast_silu(wd.x * xm3.w + wd.y * xm2.w + wd.z * xm1.w + wd.w * xc.w);
        __builtin_nontemporal_store(o, &yp[(size_t)(s0 + i) * D4]);
    }
}

extern "C" void kernel_launch(void* const* d_in, const int* in_sizes, int n_in,
                              void* d_out, int out_size, void* d_ws, size_t ws_size,
                              hipStream_t stream) {
    const float* x = (const float*)d_in[0];
    const float* w = (const float*)d_in[1];
    float* y = (float*)d_out;

    // x: (B, S, D) = (4, 4096, 2048); w: (D, 1, 4)
    const int D = in_sizes[1] / 4;     // 2048
    const int D4 = D / 4;              // 512
    const int BS = in_sizes[0] / D;    // B*S = 16384
    const int S = 4096;
    const int B = BS / S;              // 4

    const int n_stiles = S / TS;
    const long long total_threads = (long long)B * n_stiles * D4;
    const int block = 256;
    const int grid = (int)((total_threads + block - 1) / block);

    causal_conv1d_silu_kernel<<<grid, block, 0, stream>>>(
        (const float4*)x, (const float4*)w, (float4*)y, B, S, D4);
}

// Round 6
// 47.396 us; speedup vs baseline: 1.2926x; 1.0335x over previous
//
#include <hip/hip_runtime.h>
#include <hip/hip_bf16.h>

// Causal depthwise conv1d (K=4) + SiLU over x:(B,S,D) fp32, w:(D,1,4) fp32.
// y[b,s,d] = silu(sum_k w[d,k] * x[b, s-3+k, d])
//
// R5 changes vs R4 (49.0us):
//  - TS 16 -> 32: halo read ratio 1.1875 -> 1.094. The compiler streams this
//    as a sliding-window loop at VGPR=32 regardless of TS (R4 evidence), so
//    the larger tile is free in registers and cuts logical read bytes ~4%.
//  - Keep NT stores (WRITE 139MB ~ ideal) and __launch_bounds__(256,2).
// Accounting: logical 281 MB @ ~6.0 TB/s path rate -> ~47us expected.
// Current kernel is at ~95% of the m13 float4-copy path ceiling.

#define TS 32  // s-positions per thread; halo amplification (TS+3)/TS = 1.094

typedef float floatx4 __attribute__((ext_vector_type(4)));

__device__ __forceinline__ float fast_silu(float v) {
    float e = __expf(-v);
    return v * __builtin_amdgcn_rcpf(1.0f + e);
}

__global__ __launch_bounds__(256, 2) void causal_conv1d_silu_kernel(
    const float4* __restrict__ x,   // (B,S,D/4) float4
    const float4* __restrict__ w4,  // (D,) float4: w4[d] = taps k=0..3 of channel d
    float4* __restrict__ y,
    int B, int S, int D4)           // D4 = D/4
{
    const int t = blockIdx.x * blockDim.x + threadIdx.x;
    const int n_stiles = S / TS;
    const int d4 = t % D4;
    const int rest = t / D4;
    if (rest >= B * n_stiles) return;
    const int stile = rest % n_stiles;
    const int b = rest / n_stiles;
    const int s0 = stile * TS;

    const size_t base = (size_t)b * S * D4 + d4;
    const float4* xp = x + base;
    floatx4* yp = (floatx4*)(y + base);

    const float4 wa = w4[d4 * 4 + 0];
    const float4 wb = w4[d4 * 4 + 1];
    const float4 wc = w4[d4 * 4 + 2];
    const float4 wd = w4[d4 * 4 + 3];

    // Sliding window over TS rows; compiler streams this at low VGPR with
    // software-pipelined loads (R4 evidence: VGPR=32, 49us).
    const float4 zero = make_float4(0.f, 0.f, 0.f, 0.f);
    float4 xm3 = (s0 >= 3) ? xp[(size_t)(s0 - 3) * D4] : zero;
    float4 xm2 = (s0 >= 2) ? xp[(size_t)(s0 - 2) * D4] : zero;
    float4 xm1 = (s0 >= 1) ? xp[(size_t)(s0 - 1) * D4] : zero;

#pragma unroll
    for (int i = 0; i < TS; ++i) {
        const float4 xc = xp[(size_t)(s0 + i) * D4];
        floatx4 o;
        o.x = fast_silu(wa.x * xm3.x + wa.y * xm2.x + wa.z * xm1.x + wa.w * xc.x);
        o.y = fast_silu(wb.x * xm3.y + wb.y * xm2.y + wb.z * xm1.y + wb.w * xc.y);
        o.z = fast_silu(wc.x * xm3.z + wc.y * xm2.z + wc.z * xm1.z + wc.w * xc.z);
        o.w = fast_silu(wd.x * xm3.w + wd.y * xm2.w + wd.z * xm1.w + wd.w * xc.w);
        __builtin_nontemporal_store(o, &yp[(size_t)(s0 + i) * D4]);
        xm3 = xm2; xm2 = xm1; xm1 = xc;
    }
}

extern "C" void kernel_launch(void* const* d_in, const int* in_sizes, int n_in,
                              void* d_out, int out_size, void* d_ws, size_t ws_size,
                              hipStream_t stream) {
    const float* x = (const float*)d_in[0];
    const float* w = (const float*)d_in[1];
    float* y = (float*)d_out;

    // x: (B, S, D) = (4, 4096, 2048); w: (D, 1, 4)
    const int D = in_sizes[1] / 4;     // 2048
    const int D4 = D / 4;              // 512
    const int BS = in_sizes[0] / D;    // B*S = 16384
    const int S = 4096;
    const int B = BS / S;              // 4

    const int n_stiles = S / TS;
    const long long total_threads = (long long)B * n_stiles * D4;
    const int block = 256;
    const int grid = (int)((total_threads + block - 1) / block);

    causal_conv1d_silu_kernel<<<grid, block, 0, stream>>>(
        (const float4*)x, (const float4*)w, (float4*)y, B, S, D4);
}

// Round 7
// 47.056 us; speedup vs baseline: 1.3020x; 1.0072x over previous
//
#include <hip/hip_runtime.h>
#include <hip/hip_bf16.h>

// Causal depthwise conv1d (K=4) + SiLU over x:(B,S,D) fp32, w:(D,1,4) fp32.
// y[b,s,d] = silu(sum_k w[d,k] * x[b, s-3+k, d])
//
// R6 changes vs R5 (47.4us):
//  - TS 32 -> 64: halo read ratio 1.094 -> 1.047 (last reducible byte term).
//    Compiler streams the sliding window at VGPR=32 regardless of TS
//    (R4/R5 evidence), so the larger tile is free in registers.
//    Grid: 512 blocks = exactly 2 rounds on 256 CUs, 8 waves/CU -> still
//    >= 2x the ~9KB/CU latency-BW product in flight.
//  - Keep NT stores (WRITE ~ ideal+1%) and __launch_bounds__(256,2).
// Accounting at R6: 281 MB logical / 47.4us = 5.93 TB/s = 94% of m13 copy
// ceiling (6.29 TB/s). Zero-halo floor = 42.7us.

#define TS 64  // s-positions per thread; halo amplification (TS+3)/TS = 1.047

typedef float floatx4 __attribute__((ext_vector_type(4)));

__device__ __forceinline__ float fast_silu(float v) {
    float e = __expf(-v);
    return v * __builtin_amdgcn_rcpf(1.0f + e);
}

__global__ __launch_bounds__(256, 2) void causal_conv1d_silu_kernel(
    const float4* __restrict__ x,   // (B,S,D/4) float4
    const float4* __restrict__ w4,  // (D,) float4: w4[d] = taps k=0..3 of channel d
    float4* __restrict__ y,
    int B, int S, int D4)           // D4 = D/4
{
    const int t = blockIdx.x * blockDim.x + threadIdx.x;
    const int n_stiles = S / TS;
    const int d4 = t % D4;
    const int rest = t / D4;
    if (rest >= B * n_stiles) return;
    const int stile = rest % n_stiles;
    const int b = rest / n_stiles;
    const int s0 = stile * TS;

    const size_t base = (size_t)b * S * D4 + d4;
    const float4* xp = x + base;
    floatx4* yp = (floatx4*)(y + base);

    const float4 wa = w4[d4 * 4 + 0];
    const float4 wb = w4[d4 * 4 + 1];
    const float4 wc = w4[d4 * 4 + 2];
    const float4 wd = w4[d4 * 4 + 3];

    // Sliding window over TS rows; compiler streams this at VGPR=32 with
    // software-pipelined loads (R4/R5 evidence).
    const float4 zero = make_float4(0.f, 0.f, 0.f, 0.f);
    float4 xm3 = (s0 >= 3) ? xp[(size_t)(s0 - 3) * D4] : zero;
    float4 xm2 = (s0 >= 2) ? xp[(size_t)(s0 - 2) * D4] : zero;
    float4 xm1 = (s0 >= 1) ? xp[(size_t)(s0 - 1) * D4] : zero;

#pragma unroll
    for (int i = 0; i < TS; ++i) {
        const float4 xc = xp[(size_t)(s0 + i) * D4];
        floatx4 o;
        o.x = fast_silu(wa.x * xm3.x + wa.y * xm2.x + wa.z * xm1.x + wa.w * xc.x);
        o.y = fast_silu(wb.x * xm3.y + wb.y * xm2.y + wb.z * xm1.y + wb.w * xc.y);
        o.z = fast_silu(wc.x * xm3.z + wc.y * xm2.z + wc.z * xm1.z + wc.w * xc.z);
        o.w = fast_silu(wd.x * xm3.w + wd.y * xm2.w + wd.z * xm1.w + wd.w * xc.w);
        __builtin_nontemporal_store(o, &yp[(size_t)(s0 + i) * D4]);
        xm3 = xm2; xm2 = xm1; xm1 = xc;
    }
}

extern "C" void kernel_launch(void* const* d_in, const int* in_sizes, int n_in,
                              void* d_out, int out_size, void* d_ws, size_t ws_size,
                              hipStream_t stream) {
    const float* x = (const float*)d_in[0];
    const float* w = (const float*)d_in[1];
    float* y = (float*)d_out;

    // x: (B, S, D) = (4, 4096, 2048); w: (D, 1, 4)
    const int D = in_sizes[1] / 4;     // 2048
    const int D4 = D / 4;              // 512
    const int BS = in_sizes[0] / D;    // B*S = 16384
    const int S = 4096;
    const int B = BS / S;              // 4

    const int n_stiles = S / TS;
    const long long total_threads = (long long)B * n_stiles * D4;
    const int block = 256;
    const int grid = (int)((total_threads + block - 1) / block);

    causal_conv1d_silu_kernel<<<grid, block, 0, stream>>>(
        (const float4*)x, (const float4*)w, (float4*)y, B, S, D4);
}